// Round 13
// baseline (15873.529 us; speedup 1.0000x reference)
//
#include <hip/hip_runtime.h>

// ---------------------------------------------------------------------------
// LSTM classifier — persistent kernel, W-in-VGPR, FENCELESS L3 exchange.
//   B=256, T=512, E=256, H=512, VOCAB=14.
// ROUND-12: round-11 passed (absmax 2e-3) at 9.2ms; counters showed the cost
//   was __threadfence at device scope = per-step L2 writeback+invalidate on
//   all 8 XCDs (WRITE 76MB, FETCH 27MB, 18us/step). Fix: h exchanged via
//   sc0/sc1 cache-bypass ops (__hip_atomic relaxed, AGENT scope) that hit the
//   memory-side Infinity Cache (the cross-XCD coherence point) directly.
//   NO fences -> L2 keeps tbl/xsT hot; flag protocol ordered by the vmcnt(0)
//   drain inside __syncthreads (store h -> barrier -> flag ; poll -> barrier
//   -> load h).
// - input path folded into tbl[14][2048] (emb@Wx+b, gate-interleaved col=4u+g)
// - recurrent W held as bf16 MFMA B-fragments in REGISTERS (128 VGPR/wave)
// - grid 64 WGs = 8 row-groups (32 rows) x 8 unit-WGs (64 units, 512 thr);
//   group barrier = per-WG flag slots, every WG polls all 8, capped spins
// - c-state in registers; h bf16 double-buffered in global (L3-resident)
// - rows counting-sorted by length desc; group exits at its block max length
// ---------------------------------------------------------------------------

typedef __attribute__((ext_vector_type(8))) short short8;
typedef __attribute__((ext_vector_type(4))) float f32x4;

#define B_      256
#define T_      512
#define H_      512
#define GC_     2048
#define VOCAB_  14
#define NG_     8     // row groups
#define GSZ_    8     // WGs per group
#define ROWS_G  32    // rows per group
#define SPIN_CAP 100000

// ws layout (float slots)
#define TBL_OFF  0
#define H0_OFF   (VOCAB_ * GC_)            // 28672
#define H1_OFF   (H0_OFF + 65536)          // h bf16 256x512 = 65536 f-slots
#define FLG_OFF  (H1_OFF + 65536)          // 256 ints
#define SEN_OFF  (FLG_OFF + 256)           // 256 ints (unused, layout keep)
#define XST_OFF  (SEN_OFF + 256)           // int tokens [T][B]
#define PERM_OFF (XST_OFF + T_ * B_)
#define SLEN_OFF (PERM_OFF + B_)

__device__ __forceinline__ ushort f2bf(float f) {
    uint u = __float_as_uint(f);
    return (ushort)((u + 0x7fffu + ((u >> 16) & 1u)) >> 16);
}
__device__ __forceinline__ float bf2f(ushort s) {
    return __uint_as_float(((uint)s) << 16);
}

__global__ void zero_f(float* p, int n) {
    int i = blockIdx.x * blockDim.x + threadIdx.x;
    int stride = gridDim.x * blockDim.x;
    for (; i < n; i += stride) p[i] = 0.f;
}

// tbl[v*2048 + (u<<2|g)] = sum_e emb[v][e]*W_g[e][u] + b_g[u]
__global__ void build_table(const float* __restrict__ emb,
                            const float* __restrict__ Wf, const float* __restrict__ Wi,
                            const float* __restrict__ Wc, const float* __restrict__ Wo,
                            const float* __restrict__ bf, const float* __restrict__ bi,
                            const float* __restrict__ bc, const float* __restrict__ bo,
                            float* __restrict__ tbl) {
    int idx = blockIdx.x * 256 + threadIdx.x;
    if (idx >= VOCAB_ * GC_) return;
    int v = idx >> 11, cc = idx & 2047, u = cc >> 2, g = cc & 3;
    const float* W = (g == 0) ? Wf : (g == 1) ? Wi : (g == 2) ? Wc : Wo;
    const float* b = (g == 0) ? bf : (g == 1) ? bi : (g == 2) ? bc : bo;
    float s = b[u];
    const float* ev = emb + v * 256;
    for (int e = 0; e < 256; ++e) s += ev[e] * W[e * H_ + u];
    tbl[idx] = s;
}

// counting sort by length descending
__global__ void sortlen(const int* __restrict__ lengths,
                        int* __restrict__ perm, int* __restrict__ slen) {
    __shared__ int cnt[513];
    __shared__ int off[513];
    int tid = threadIdx.x;  // 1024
    if (tid < 513) cnt[tid] = 0;
    __syncthreads();
    if (tid < B_) atomicAdd(&cnt[lengths[tid]], 1);
    __syncthreads();
    if (tid <= 512) {
        int s = 0;
        for (int L = tid + 1; L <= 512; ++L) s += cnt[L];
        off[tid] = s;
    }
    __syncthreads();
    if (tid < B_) {
        int L = lengths[tid];
        int p = atomicAdd(&off[L], 1);
        perm[p] = tid;
        slen[p] = L;
    }
}

__global__ void gatherx(const int* __restrict__ x, const int* __restrict__ perm,
                        int* __restrict__ xsT) {
    int t = blockIdx.x;
    int r = threadIdx.x;
    xsT[t * B_ + r] = x[perm[r] * T_ + t];
}

// ---------------------------------------------------------------------------
// Persistent kernel. 64 WGs x 512 threads (8 waves).
// WG (g = bid&7, jb = bid>>3): rows g*32..+32, units jb*64..+64.
// Wave w: units jb*64 + w*8 ..+8 (32 gate cols = 2 N-tiles of 16).
// B-fragments for mfma_f32_16x16x32_bf16 live in VGPRs (bfr[2][16], 128 regs).
// h exchange: uint (2xbf16) relaxed AGENT atomics = sc0/sc1 L1/L2-bypass,
// coherent at the memory-side L3. No fences anywhere in the loop.
// ---------------------------------------------------------------------------
__global__ __launch_bounds__(512, 1) void lstm_persist(
    const float* __restrict__ Wf, const float* __restrict__ Wi,
    const float* __restrict__ Wc, const float* __restrict__ Wo,
    const float* __restrict__ tbl, const int* __restrict__ xsT,
    const int* __restrict__ slen, ushort* __restrict__ h0,
    ushort* __restrict__ h1, int* __restrict__ flg) {
    const int bid = blockIdx.x;
    const int g   = bid & 7;      // row-group
    const int jb  = bid >> 3;     // unit-block (64 units)
    const int tid = threadIdx.x;
    const int w    = tid >> 6;    // wave 0..7
    const int lane = tid & 63;
    const int grow0 = g * ROWS_G;

    __shared__ float xch[8 * 32 * 36];   // per-wave [32 gc][36] bounce, 36 KB

    // ---- preload recurrent W as B-fragments in registers ----
    // B-layout (16x16x32): lane l holds col n=l&15, k = (l>>4)*8 + jj.
    // col n -> unit (n>>2) of the N-tile, gate = n&3; value = W_g[256+k][unit].
    short8 bfr[2][16];
    {
        const int n = lane & 15, q = lane >> 4, gg = n & 3;
        const float* Wg = (gg == 0) ? Wf : (gg == 1) ? Wi : (gg == 2) ? Wc : Wo;
#pragma unroll
        for (int nt = 0; nt < 2; ++nt) {
            int ucol = jb * 64 + w * 8 + nt * 4 + (n >> 2);
#pragma unroll
            for (int kt = 0; kt < 16; ++kt) {
                short8 bb;
#pragma unroll
                for (int jj = 0; jj < 8; ++jj) {
                    ((ushort*)&bb)[jj] = f2bf(Wg[(256 + kt * 32 + q * 8 + jj) * H_ + ucol]);
                }
                bfr[nt][kt] = bb;
            }
        }
    }

    // ---- per-lane state ----
    const int tmax = slen[grow0];              // group max (sorted desc)
    const int u_e = lane & 7, r4 = lane >> 3;  // epilogue: unit, row residue
    const int ug = jb * 64 + w * 8 + u_e;      // global unit
    float c[4];
    int lenr[4];
#pragma unroll
    for (int rr = 0; rr < 4; ++rr) {
        c[rr] = 0.f;
        lenr[rr] = slen[grow0 + rr * 8 + r4];
    }
    float* xw = &xch[w * 1152];
    int* myflg = &flg[g * GSZ_];
    const int rA = grow0 + (lane & 15);        // A-frag row (mt=0)
    const int ko = (lane >> 4) * 8;            // A-frag k offset
    const int baseA0 = (rA * H_ + ko) >> 1;          // uint index into h
    const int baseA1 = ((rA + 16) * H_ + ko) >> 1;

    union U8 { uint u[4]; short8 s; };

    for (int t = 0; t < tmax; ++t) {
        const uint* hcu = (const uint*)((t & 1) ? h1 : h0);
        ushort* hn = (t & 1) ? h0 : h1;

        // ---- gates = h @ Wpack : 2 M-tiles x 2 N-tiles x 16 K-tiles ----
        // A-frags via relaxed AGENT atomic uint loads (sc0/sc1: read L3,
        // bypass stale L1/L2; independent loads, scheduler may hoist).
        f32x4 a00 = {0.f,0.f,0.f,0.f}, a01 = {0.f,0.f,0.f,0.f};
        f32x4 a10 = {0.f,0.f,0.f,0.f}, a11 = {0.f,0.f,0.f,0.f};
#pragma unroll
        for (int kt = 0; kt < 16; ++kt) {
            U8 c0, c1;
#pragma unroll
            for (int q = 0; q < 4; ++q) {
                c0.u[q] = __hip_atomic_load((uint*)&hcu[baseA0 + kt * 16 + q],
                                            __ATOMIC_RELAXED, __HIP_MEMORY_SCOPE_AGENT);
                c1.u[q] = __hip_atomic_load((uint*)&hcu[baseA1 + kt * 16 + q],
                                            __ATOMIC_RELAXED, __HIP_MEMORY_SCOPE_AGENT);
            }
            a00 = __builtin_amdgcn_mfma_f32_16x16x32_bf16(c0.s, bfr[0][kt], a00, 0, 0, 0);
            a01 = __builtin_amdgcn_mfma_f32_16x16x32_bf16(c0.s, bfr[1][kt], a01, 0, 0, 0);
            a10 = __builtin_amdgcn_mfma_f32_16x16x32_bf16(c1.s, bfr[0][kt], a10, 0, 0, 0);
            a11 = __builtin_amdgcn_mfma_f32_16x16x32_bf16(c1.s, bfr[1][kt], a11, 0, 0, 0);
        }

        // ---- bounce acc -> xw[gc_loc][row] (wave-private, no barrier) ----
        {
            int n = lane & 15, qq = (lane >> 4) * 4;
            *(f32x4*)&xw[n * 36 + qq]             = a00;
            *(f32x4*)&xw[(16 + n) * 36 + qq]      = a01;
            *(f32x4*)&xw[n * 36 + 16 + qq]        = a10;
            *(f32x4*)&xw[(16 + n) * 36 + 16 + qq] = a11;
        }

        // ---- activations + state update: 4 (row,unit) pairs per lane ----
#pragma unroll
        for (int rr = 0; rr < 4; ++rr) {
            int row = rr * 8 + r4;
            int tok = xsT[t * B_ + grow0 + row];
            f32x4 tb = *(const f32x4*)&tbl[tok * GC_ + ug * 4];
            int gl = (u_e >> 2) * 16 + (u_e & 3) * 4;
            float pf = xw[(gl + 0) * 36 + row] + tb.x;
            float pi = xw[(gl + 1) * 36 + row] + tb.y;
            float pc = xw[(gl + 2) * 36 + row] + tb.z;
            float po = xw[(gl + 3) * 36 + row] + tb.w;
            float fg = 1.f / (1.f + __expf(-pf));
            float ig = 1.f / (1.f + __expf(-pi));
            float cg = 2.f / (1.f + __expf(-2.f * pc)) - 1.f;
            float og = 1.f / (1.f + __expf(-po));
            float cn = fg * c[rr] + ig * cg;
            float hh = og * (2.f / (1.f + __expf(-2.f * cn)) - 1.f);
            float hp = __shfl_xor(hh, 1);   // partner lane = unit ug^1, same row
            if (t < lenr[rr]) {             // freeze row at its length
                c[rr] = cn;
                if (!(lane & 1)) {          // even lane stores both units packed
                    uint hv = (uint)f2bf(hh) | ((uint)f2bf(hp) << 16);
                    __hip_atomic_store((uint*)&hn[(grow0 + row) * H_ + ug], hv,
                                       __ATOMIC_RELAXED, __HIP_MEMORY_SCOPE_AGENT);
                }
            }
        }

        // ---- group barrier: flag slots, no fences ----
        // __syncthreads drains vmcnt(0): our h stores reached L3 before flag.
        __syncthreads();
        if (tid == 0)
            __hip_atomic_store(&myflg[jb], t + 1, __ATOMIC_RELAXED,
                               __HIP_MEMORY_SCOPE_AGENT);
        if (tid < GSZ_) {                 // wave-0 lanes poll all 8 flags
            int sp = 0;
            while (__hip_atomic_load(&myflg[tid], __ATOMIC_RELAXED,
                                     __HIP_MEMORY_SCOPE_AGENT) <= t) {
                __builtin_amdgcn_s_sleep(1);
                if (++sp > SPIN_CAP) break;
            }
        }
        __syncthreads();                  // pollers gate the whole WG
    }
}

// out[perm[r]] = sigmoid(dot(h_final[r], fcW) + fcb); h_final in buf[len&1]
__global__ void fc_out(const ushort* __restrict__ h0, const ushort* __restrict__ h1,
                       const float* __restrict__ fcW, const float* __restrict__ fcb,
                       const int* __restrict__ perm, const int* __restrict__ slen,
                       float* __restrict__ out) {
    int r = blockIdx.x;
    int lane = threadIdx.x;  // 64
    const ushort* h = (((slen[r] & 1) ? h1 : h0)) + r * H_;
    float s = 0.f;
    for (int j = lane; j < H_; j += 64) s += bf2f(h[j]) * fcW[j];
#pragma unroll
    for (int o = 32; o > 0; o >>= 1) s += __shfl_down(s, o);
    if (lane == 0) {
        out[perm[r]] = 1.f / (1.f + expf(-(s + fcb[0])));
    }
}

// ---------------------------------------------------------------------------
extern "C" void kernel_launch(void* const* d_in, const int* in_sizes, int n_in,
                              void* d_out, int out_size, void* d_ws, size_t ws_size,
                              hipStream_t stream) {
    const int* x   = (const int*)d_in[0];
    const int* len = (const int*)d_in[1];
    const float* emb = (const float*)d_in[2];
    const float* Wf  = (const float*)d_in[3];
    const float* bfp = (const float*)d_in[4];
    const float* Wi  = (const float*)d_in[5];
    const float* bip = (const float*)d_in[6];
    const float* Wc  = (const float*)d_in[7];
    const float* bcp = (const float*)d_in[8];
    const float* Wo  = (const float*)d_in[9];
    const float* bop = (const float*)d_in[10];
    const float* fcW = (const float*)d_in[11];
    const float* fcb = (const float*)d_in[12];
    float* out = (float*)d_out;

    float* wsf = (float*)d_ws;
    float*  tbl  = wsf + TBL_OFF;
    ushort* h0   = (ushort*)(wsf + H0_OFF);
    ushort* h1   = (ushort*)(wsf + H1_OFF);
    int*    flg  = (int*)(wsf + FLG_OFF);
    int*    xsT  = (int*)(wsf + XST_OFF);
    int*    perm = (int*)(wsf + PERM_OFF);
    int*    slen = (int*)(wsf + SLEN_OFF);

    // zero h0,h1,flg,sen (contiguous; ws re-poisoned before every call)
    zero_f<<<512, 256, 0, stream>>>(wsf + H0_OFF, 2 * 65536 + 512);
    build_table<<<(VOCAB_ * GC_ + 255) / 256, 256, 0, stream>>>(
        emb, Wf, Wi, Wc, Wo, bfp, bip, bcp, bop, tbl);
    sortlen<<<1, 1024, 0, stream>>>(len, perm, slen);
    gatherx<<<T_, B_, 0, stream>>>(x, perm, xsT);

    lstm_persist<<<NG_ * GSZ_, 512, 0, stream>>>(
        Wf, Wi, Wc, Wo, tbl, xsT, slen, h0, h1, flg);

    fc_out<<<B_, 64, 0, stream>>>(h0, h1, fcW, fcb, perm, slen, out);
}